// Round 7
// baseline (533.266 us; speedup 1.0000x reference)
//
#include <hip/hip_runtime.h>
#include <hip/hip_bf16.h>
#include <cstdint>
#include <cstddef>

typedef unsigned short u16;
typedef unsigned int   u32;

typedef __bf16 bf8   __attribute__((ext_vector_type(8)));
typedef float  f32x4 __attribute__((ext_vector_type(4)));

__device__ __forceinline__ float b2f(u16 v) {
  union { u32 i; float f; } c; c.i = ((u32)v) << 16; return c.f;
}
__device__ __forceinline__ u16 f2b(float f) {
  union { u32 i; float f; } c; c.f = f;
  u32 x = c.i;
  u32 r = (x + 0x7FFFu + ((x >> 16) & 1u)) >> 16;
  return (u16)r;
}
__device__ __forceinline__ float sigf(float x) { return 1.0f / (1.0f + __expf(-x)); }
__device__ __forceinline__ float tanhfast(float x) { return 2.0f * sigf(2.0f * x) - 1.0f; }

__device__ __forceinline__ bf8 cvt8(const float* __restrict__ p) {
  f32x4 lo = *(const f32x4*)p;
  f32x4 hi = *(const f32x4*)(p + 4);
  union { u16 s[8]; bf8 v; } c;
#pragma unroll
  for (int i = 0; i < 4; ++i) { c.s[i] = f2b(lo[i]); c.s[4 + i] = f2b(hi[i]); }
  return c.v;
}
__device__ __forceinline__ bf8 asbf8(uint4 q) {
  union { uint4 q; bf8 v; } c; c.q = q; return c.v;
}

// async 16B global -> LDS (dest = wave-uniform base + lane*16)
__device__ __forceinline__ void ld_lds16(const u16* g, u16* l) {
  __builtin_amdgcn_global_load_lds((const __attribute__((address_space(1))) void*)g,
                                   (__attribute__((address_space(3))) void*)l, 16, 0, 0);
}

#define CSR_STRIDE 80

// ---- weight repack: W fp32 [K x 128] -> Bt bf16 in MFMA-fragment order ----
// frag f = (hh*4+ks)*512 + c*64 + lane ; elem j: W[(hh*128+ks*32+quad*8+j)*128 + (c*16+ln)]
// blocks >= 64 zero the degree-count array.
__global__ __launch_bounds__(256) void k_transpose(
    const float* __restrict__ W0, const float* __restrict__ W1,
    const float* __restrict__ W2, const float* __restrict__ W3,
    const float* __restrict__ W4,
    u16* __restrict__ B0, u16* __restrict__ B1, u16* __restrict__ B2,
    u16* __restrict__ B3, u16* __restrict__ B4,
    int* __restrict__ cnt, int N) {
  if (blockIdx.x >= 64) {
    int i = (blockIdx.x - 64) * 256 + threadIdx.x;
    if (i < N) cnt[i] = 0;
    return;
  }
  int t = blockIdx.x * 256 + threadIdx.x;
  const float* in; u16* out; int f;
  if (t < 2048)       { in = W0; out = B0; f = t; }
  else if (t < 4096)  { in = W1; out = B1; f = t - 2048; }
  else if (t < 8192)  { in = W2; out = B2; f = t - 4096; }
  else if (t < 12288) { in = W3; out = B3; f = t - 8192; }
  else                { in = W4; out = B4; f = t - 12288; }
  int ln = f & 15, quad = (f >> 4) & 3, c = (f >> 6) & 7, ks = (f >> 9) & 3, hh = f >> 11;
  int n = c * 16 + ln;
  int k0 = hh * 128 + ks * 32 + quad * 8;
  union { u16 s[8]; uint4 q; } tmp;
#pragma unroll
  for (int j = 0; j < 8; ++j) tmp.s[j] = f2b(in[(size_t)(k0 + j) * 128 + n]);
  *(uint4*)(out + (size_t)f * 8) = tmp.q;
}

// ---------------- CSR build + h->bf16 convert ----------------
__global__ void k_fill(const int* __restrict__ src, const int* __restrict__ dst,
                       int* __restrict__ cnt, int* __restrict__ csr, int E,
                       const float* __restrict__ h, u16* __restrict__ hb, int HV8) {
  int i = blockIdx.x * 256 + threadIdx.x;
  if (i < E) {
    int d = dst[i];
    int pos = atomicAdd(&cnt[d], 1);
    if (pos < CSR_STRIDE) csr[(size_t)d * CSR_STRIDE + pos] = src[i];
  }
  if (i < HV8) {
    const float* p = h + (size_t)i * 8;
    f32x4 lo = *(const f32x4*)p, hi = *(const f32x4*)(p + 4);
    union { u16 s[8]; uint4 q; } o;
#pragma unroll
    for (int j = 0; j < 4; ++j) { o.s[j] = f2b(lo[j]); o.s[4 + j] = f2b(hi[j]); }
    ((uint4*)hb)[i] = o.q;
  }
}

// ---------------- aggregation: 16 lanes per node, 16 gathers in flight ----------------
// out[d] = postproc( rsqrt(deg+1) * (sum_{s->d} y[s] + y[d]) + bias )
__global__ __launch_bounds__(256) void k_agg(const u16* __restrict__ y,
                                             const int* __restrict__ cnt,
                                             const int* __restrict__ csr,
                                             const float* __restrict__ bias,
                                             u16* __restrict__ out, int relu, int N) {
  int gid = (blockIdx.x * 256 + threadIdx.x) >> 4;   // one 16-lane group per node
  int lane = threadIdx.x & 63;
  int t = lane & 15;
  if (gid >= N) return;
  int deg0 = cnt[gid];
  int deg = (deg0 < CSR_STRIDE) ? deg0 : CSR_STRIDE;
  long base = (long)gid * CSR_STRIDE;
  const uint4* yq = (const uint4*)y;

  float2 a[4];
#pragma unroll
  for (int i = 0; i < 4; ++i) { a[i].x = 0.0f; a[i].y = 0.0f; }

  uint4 sv = yq[(size_t)gid * 16 + t];      // self row (in flight early)

  for (int j0 = 0; j0 < deg; j0 += 16) {
    int cc = deg - j0; if (cc > 16) cc = 16;
    int my = (t < cc) ? csr[base + j0 + t] : 0;
    int sl[16];
#pragma unroll
    for (int k = 0; k < 16; ++k)
      sl[k] = __shfl(my, (lane & 48) | ((k < cc) ? k : 0), 64);
    uint4 v[16];
#pragma unroll
    for (int k = 0; k < 16; ++k) v[k] = yq[(size_t)sl[k] * 16 + t];
#pragma unroll
    for (int k = 0; k < 16; ++k) {
      if (k < cc) {
        const __hip_bfloat162* pb = (const __hip_bfloat162*)&v[k];
#pragma unroll
        for (int i = 0; i < 4; ++i) {
          float2 f = __bfloat1622float2(pb[i]);
          a[i].x += f.x; a[i].y += f.y;
        }
      }
    }
  }
  {
    const __hip_bfloat162* pb = (const __hip_bfloat162*)&sv;
#pragma unroll
    for (int i = 0; i < 4; ++i) {
      float2 f = __bfloat1622float2(pb[i]);
      a[i].x += f.x; a[i].y += f.y;
    }
  }
  float di = rsqrtf((float)deg0 + 1.0f);
  f32x4 b0 = *(const f32x4*)(bias + t * 8);
  f32x4 b1 = *(const f32x4*)(bias + t * 8 + 4);
  union { u16 s[8]; uint4 q; } o;
#pragma unroll
  for (int i = 0; i < 4; ++i) {
    float r0 = di * a[i].x + ((2 * i < 4) ? b0[2 * i] : b1[2 * i - 4]);
    float r1 = di * a[i].y + ((2 * i + 1 < 4) ? b0[2 * i + 1] : b1[2 * i - 3]);
    if (relu) { r0 = fmaxf(r0, 0.0f); r1 = fmaxf(r1, 0.0f); }
    o.s[2 * i] = f2b(r0); o.s[2 * i + 1] = f2b(r1);
  }
  ((uint4*)out)[(size_t)gid * 16 + t] = o.q;
}

// ---------------- layer GEMM: y[M,128] = bf16( (A[M,128] @ W) * rsqrt(deg+1)[row] ) ----------------
template <bool AF>
__global__ __launch_bounds__(256) void k_gemm(
    const void* __restrict__ Av,
    const u16* __restrict__ Bt,
    const int* __restrict__ cnt,
    u16* __restrict__ outb, int M) {
  __shared__ __align__(16) u16 bs[16384];
  int tid = threadIdx.x;
  int lane = tid & 63, wave = tid >> 6;
  int ln = lane & 15, quad = lane >> 4;
  int rowbase = blockIdx.x * 64 + wave * 16;
  int rowA = rowbase + ln;
  long rA = (rowA < M) ? rowA : (M - 1);

  {
    const u16* g = Bt + wave * 4096 + lane * 8;
    u16* l = bs + wave * 4096;
#pragma unroll
    for (int i = 0; i < 8; ++i) ld_lds16(g + i * 512, l + i * 512);
  }

  bf8 af[4];
#pragma unroll
  for (int ks = 0; ks < 4; ++ks) {
    int kk = ks * 32 + quad * 8;
    if (AF) af[ks] = cvt8((const float*)Av + rA * 128 + kk);
    else    af[ks] = *(const bf8*)((const u16*)Av + rA * 128 + kk);
  }

  f32x4 acc[8];
#pragma unroll
  for (int c = 0; c < 8; ++c) { acc[c][0] = 0.f; acc[c][1] = 0.f; acc[c][2] = 0.f; acc[c][3] = 0.f; }

  __syncthreads();
#pragma unroll
  for (int ks = 0; ks < 4; ++ks) {
#pragma unroll
    for (int c = 0; c < 8; ++c) {
      bf8 bfr = *(const bf8*)(bs + ks * 4096 + c * 512 + lane * 8);
      acc[c] = __builtin_amdgcn_mfma_f32_16x16x32_bf16(af[ks], bfr, acc[c], 0, 0, 0);
    }
  }

  int rb = rowbase + quad * 4;
  float rs[4];
#pragma unroll
  for (int r = 0; r < 4; ++r) {
    int row = rb + r;
    rs[r] = (row < M) ? rsqrtf((float)cnt[row] + 1.0f) : 0.0f;
  }
#pragma unroll
  for (int c = 0; c < 8; ++c) {
    int col = c * 16 + ln;
#pragma unroll
    for (int r = 0; r < 4; ++r) {
      int row = rb + r;
      if (row < M) outb[(size_t)row * 128 + col] = f2b(acc[c][r] * rs[r]);
    }
  }
}

// ---------------- fused GRU, persistent: Wz+Wr staged ONCE, 1 barrier, tile loop ----------------
// 512 threads (8 waves), 128-row tiles, grid 256. Wc streamed from L2 (2-deep ping-pong).
#define AT_STRIDE 72
__global__ __launch_bounds__(512, 1) void k_gru(
    const u16* __restrict__ emb, const u16* __restrict__ hb,
    const u16* __restrict__ Btz, const u16* __restrict__ Btr, const u16* __restrict__ Btc,
    const float* __restrict__ bz, const float* __restrict__ br, const float* __restrict__ bc,
    float* __restrict__ out, int M) {
  __shared__ __align__(16) u16 bs[65536];            // 128 KB: Wz [0..32767], Wr [32768..65535]
  __shared__ __align__(16) u16 at[8 * 16 * AT_STRIDE];  // 18 KB: wave-private rh tiles
  int tid = threadIdx.x;
  int lane = tid & 63, wave = tid >> 6;
  int ln = lane & 15, quad = lane >> 4;
  u16* atw = at + wave * 16 * AT_STRIDE;

  // stage Wz, Wr once (async DMA, 16 x 16B per thread)
#pragma unroll
  for (int i = 0; i < 8; ++i) {
    int fi = i * 512 + tid;
    ld_lds16(Btz + (size_t)fi * 8, bs + (size_t)fi * 8);
  }
#pragma unroll
  for (int i = 0; i < 8; ++i) {
    int fi = i * 512 + tid;
    ld_lds16(Btr + (size_t)fi * 8, bs + 32768 + (size_t)fi * 8);
  }
  __syncthreads();                                   // the ONLY barrier

  const uint4* Bc = (const uint4*)Btc;
  int numTiles = (M + 127) >> 7;

  for (int tile = blockIdx.x; tile < numTiles; tile += gridDim.x) {
    int rowbase = tile * 128 + wave * 16;
    int rowA = rowbase + ln;
    long rA = (rowA < M) ? rowA : (M - 1);
    int rb = rowbase + quad * 4;

    bf8 af_e[4], af_h[4];
#pragma unroll
    for (int ks = 0; ks < 4; ++ks) {
      af_e[ks] = *(const bf8*)(emb + rA * 128 + ks * 32 + quad * 8);
      af_h[ks] = *(const bf8*)(hb + rA * 128 + ks * 32 + quad * 8);
    }
    // h at C-layout positions (bf16 source)
    f32x4 hc[8];
#pragma unroll
    for (int c = 0; c < 8; ++c) {
      int col = c * 16 + ln;
#pragma unroll
      for (int r = 0; r < 4; ++r) {
        int row = rb + r;
        hc[c][r] = (row < M) ? b2f(hb[(size_t)row * 128 + col]) : 0.0f;
      }
    }

    f32x4 accz[8], accr[8];
#pragma unroll
    for (int c = 0; c < 8; ++c) {
      accz[c][0] = 0.f; accz[c][1] = 0.f; accz[c][2] = 0.f; accz[c][3] = 0.f;
      accr[c][0] = 0.f; accr[c][1] = 0.f; accr[c][2] = 0.f; accr[c][3] = 0.f;
    }

    // z/r pass from LDS
#pragma unroll
    for (int ksg = 0; ksg < 8; ++ksg) {
      bf8 af = (ksg < 4) ? af_e[ksg] : af_h[ksg - 4];
#pragma unroll
      for (int c = 0; c < 8; ++c) {
        bf8 vz = *(const bf8*)(bs + ((size_t)ksg * 512 + c * 64 + lane) * 8);
        accz[c] = __builtin_amdgcn_mfma_f32_16x16x32_bf16(af, vz, accz[c], 0, 0, 0);
        bf8 vr = *(const bf8*)(bs + 32768 + ((size_t)ksg * 512 + c * 64 + lane) * 8);
        accr[c] = __builtin_amdgcn_mfma_f32_16x16x32_bf16(af, vr, accr[c], 0, 0, 0);
      }
    }

    // u = sig(accz+bz); rh = sig(accr+br)*h  -> wave-private at (2 phases), no barrier
    bf8 af_at[4];
#pragma unroll
    for (int c = 0; c < 4; ++c) {                 // phase A: cols 0..63
      int col = c * 16 + ln;
      float bzc = bz[col], brc = br[col];
#pragma unroll
      for (int r = 0; r < 4; ++r) {
        float uu = sigf(accz[c][r] + bzc);
        float rr = sigf(accr[c][r] + brc);
        accz[c][r] = uu;
        atw[(quad * 4 + r) * AT_STRIDE + col] = f2b(rr * hc[c][r]);
        accr[c][r] = 0.0f;
      }
    }
#pragma unroll
    for (int ks = 0; ks < 2; ++ks)
      af_at[ks] = *(const bf8*)(atw + ln * AT_STRIDE + ks * 32 + quad * 8);
#pragma unroll
    for (int c = 4; c < 8; ++c) {                 // phase B: cols 64..127
      int col = c * 16 + ln;
      float bzc = bz[col], brc = br[col];
#pragma unroll
      for (int r = 0; r < 4; ++r) {
        float uu = sigf(accz[c][r] + bzc);
        float rr = sigf(accr[c][r] + brc);
        accz[c][r] = uu;
        atw[(quad * 4 + r) * AT_STRIDE + (col - 64)] = f2b(rr * hc[c][r]);
        accr[c][r] = 0.0f;
      }
    }
#pragma unroll
    for (int ks = 2; ks < 4; ++ks)
      af_at[ks] = *(const bf8*)(atw + ln * AT_STRIDE + (ks - 2) * 32 + quad * 8);

    // c pass: Wc streamed from L2, ping-pong
    uint4 cb[2][8];
    auto loadc = [&](int buf, int ksg) {
#pragma unroll
      for (int c = 0; c < 8; ++c) cb[buf][c] = Bc[(size_t)ksg * 512 + c * 64 + lane];
    };
    auto mfc = [&](int buf, int ksg) {
      bf8 af = (ksg < 4) ? af_e[ksg] : af_at[ksg - 4];
#pragma unroll
      for (int c = 0; c < 8; ++c)
        accr[c] = __builtin_amdgcn_mfma_f32_16x16x32_bf16(af, asbf8(cb[buf][c]), accr[c], 0, 0, 0);
    };
    loadc(0, 0); loadc(1, 1);
    mfc(0, 0); loadc(0, 2);
    mfc(1, 1); loadc(1, 3);
    mfc(0, 2); loadc(0, 4);
    mfc(1, 3); loadc(1, 5);
    mfc(0, 4); loadc(0, 6);
    mfc(1, 5); loadc(1, 7);
    mfc(0, 6); mfc(1, 7);

    // epilogue: out = (1-u)*h + u*tanh(accc + bc)
#pragma unroll
    for (int c = 0; c < 8; ++c) {
      int col = c * 16 + ln;
      float bcc = bc[col];
#pragma unroll
      for (int r = 0; r < 4; ++r) {
        int row = rb + r;
        if (row < M) {
          float cd = tanhfast(accr[c][r] + bcc);
          float uu = accz[c][r];
          out[(size_t)row * 128 + col] = (1.0f - uu) * hc[c][r] + uu * cd;
        }
      }
    }
  }
}

extern "C" void kernel_launch(void* const* d_in, const int* in_sizes, int n_in,
                              void* d_out, int out_size, void* d_ws, size_t ws_size,
                              hipStream_t stream) {
  const float* x     = (const float*)d_in[0];
  const float* h     = (const float*)d_in[1];
  const int*   ei    = (const int*)d_in[2];
  const float* W_in  = (const float*)d_in[3];
  const float* b_in  = (const float*)d_in[4];
  const float* W_hid = (const float*)d_in[5];
  const float* b_hid = (const float*)d_in[6];
  const float* W_z   = (const float*)d_in[7];
  const float* b_z   = (const float*)d_in[8];
  const float* W_r   = (const float*)d_in[9];
  const float* b_r   = (const float*)d_in[10];
  const float* W_c   = (const float*)d_in[11];
  const float* b_c   = (const float*)d_in[12];

  const int N = in_sizes[0] / 128;
  const int E = in_sizes[2] / 2;
  const int* src = ei;
  const int* dst = ei + E;

  char* p = (char*)d_ws;
  auto carve = [&](size_t bytes) { char* r = p; p += (bytes + 255) & ~(size_t)255; return r; };
  u16* Bt_in   = (u16*)carve((size_t)16384 * 2);
  u16* Bt_hid  = (u16*)carve((size_t)16384 * 2);
  u16* Bt_z    = (u16*)carve((size_t)32768 * 2);
  u16* Bt_r    = (u16*)carve((size_t)32768 * 2);
  u16* Bt_c    = (u16*)carve((size_t)32768 * 2);
  int* cnt  = (int*)carve((size_t)N * 4);
  int* csr  = (int*)carve((size_t)N * CSR_STRIDE * 4);
  u16* y    = (u16*)carve((size_t)N * 128 * 2);
  u16* h1   = (u16*)carve((size_t)N * 128 * 2);
  u16* emb  = (u16*)carve((size_t)N * 128 * 2);
  u16* hb   = (u16*)carve((size_t)N * 128 * 2);

  int gN = (N + 255) / 256;
  int HV8 = N * 16;                       // N*128/8 vec8 groups for h->bf16
  int gF = (HV8 + 255) / 256;             // covers E too (HV8 > E here)
  if (gF < (E + 255) / 256) gF = (E + 255) / 256;
  int gG = (N + 63) / 64;
  int gA = (N + 15) / 16;

  k_transpose<<<64 + gN, 256, 0, stream>>>(W_in, W_hid, W_z, W_r, W_c,
                                           Bt_in, Bt_hid, Bt_z, Bt_r, Bt_c, cnt, N);
  k_fill<<<gF, 256, 0, stream>>>(src, dst, cnt, csr, E, h, hb, HV8);

  // layer 1
  k_gemm<true><<<gG, 256, 0, stream>>>(x, Bt_in, cnt, y, N);
  k_agg<<<gA, 256, 0, stream>>>(y, cnt, csr, b_in, h1, 1, N);
  // layer 2
  k_gemm<false><<<gG, 256, 0, stream>>>(h1, Bt_hid, cnt, y, N);
  k_agg<<<gA, 256, 0, stream>>>(y, cnt, csr, b_hid, emb, 0, N);
  // fused GRU (persistent)
  k_gru<<<256, 512, 0, stream>>>(emb, hb, Bt_z, Bt_r, Bt_c, b_z, b_r, b_c, (float*)d_out, N);
}